// Round 7
// baseline (23024.123 us; speedup 1.0000x reference)
//
#include <hip/hip_runtime.h>
#include <math.h>

#define NTH 128
#define XW 28      // X row width ([c][v] layout, cols 25..27 pad)
#define CP 68      // T row width ([v][c] layout, cols 64..67 pad)
#define NV 28

__device__ __forceinline__ float tanh_fast(float x) {
    float t = fminf(fmaxf(2.0f * x, -30.0f), 30.0f);
    float e = __expf(t);
    return (e - 1.0f) / (e + 1.0f);
}

// T[v][c] = sum_u X[c][u] * As[v][u]   (pure matmul; pe is pre-added into X)
__device__ __forceinline__ void amul(const float* __restrict__ X, float* __restrict__ T,
                                     const float* __restrict__ As, int o0, int o1, int vs)
{
    float a0[7], a1[7];
    #pragma unroll
    for (int j = 0; j < 7; ++j) { a0[j] = 0.f; a1[j] = 0.f; }
    const float* x0p = X + o0 * XW;
    const float* x1p = X + o1 * XW;
    #pragma unroll
    for (int ub = 0; ub < 7; ++ub) {
        float4 x0 = *(const float4*)(x0p + 4 * ub);
        float4 x1 = *(const float4*)(x1p + 4 * ub);
        #pragma unroll
        for (int j = 0; j < 7; ++j) {
            float4 a = *(const float4*)(As + (vs + 4 * j) * XW + 4 * ub);
            a0[j] = fmaf(x0.x, a.x, fmaf(x0.y, a.y, fmaf(x0.z, a.z, fmaf(x0.w, a.w, a0[j]))));
            a1[j] = fmaf(x1.x, a.x, fmaf(x1.y, a.y, fmaf(x1.z, a.z, fmaf(x1.w, a.w, a1[j]))));
        }
    }
    #pragma unroll
    for (int j = 0; j < 7; ++j) {
        int v = vs + 4 * j;
        T[v * CP + o0] = a0[j];
        T[v * CP + o1] = a1[j];
    }
}

// TOX=true: X[o][v] = tanh(acc) ; TOX=false: Tout[v][c] = tanh(acc)
template<bool TOX>
__device__ __forceinline__ void wmul(const float* __restrict__ T, float* __restrict__ outp,
                                     const float* __restrict__ Wg, float b0, float b1,
                                     int o0, int o1, int vs)
{
    float a0[7], a1[7];
    #pragma unroll
    for (int j = 0; j < 7; ++j) { a0[j] = b0; a1[j] = b1; }
    const float* w0p = Wg + o0 * 64;
    const float* w1p = Wg + o1 * 64;
    #pragma unroll
    for (int cb = 0; cb < 16; ++cb) {
        float4 w0 = *(const float4*)(w0p + 4 * cb);
        float4 w1 = *(const float4*)(w1p + 4 * cb);
        #pragma unroll
        for (int j = 0; j < 7; ++j) {
            float4 t = *(const float4*)(T + (vs + 4 * j) * CP + 4 * cb);
            a0[j] = fmaf(w0.x, t.x, fmaf(w0.y, t.y, fmaf(w0.z, t.z, fmaf(w0.w, t.w, a0[j]))));
            a1[j] = fmaf(w1.x, t.x, fmaf(w1.y, t.y, fmaf(w1.z, t.z, fmaf(w1.w, t.w, a1[j]))));
        }
    }
    #pragma unroll
    for (int j = 0; j < 7; ++j) {
        int v = vs + 4 * j;
        if (TOX) { outp[o0 * XW + v] = tanh_fast(a0[j]); outp[o1 * XW + v] = tanh_fast(a1[j]); }
        else     { outp[v * CP + o0] = tanh_fast(a0[j]); outp[v * CP + o1] = tanh_fast(a1[j]); }
    }
}

// First 3 layers of f: X -> (A,W1,tanh) -> (A,W2,tanh) -> (A,W3,tanh) -> Tb[v][c].
// Touches only LDS; no local-array addresses escape.
__device__ __forceinline__ void ode_head(float* X, float* Ta, float* Tb, const float* As,
    const float* W1, float b10, float b11, const float* W2, float b20, float b21,
    const float* W3, float b30, float b31, int o0, int o1, int vs)
{
    amul(X, Ta, As, o0, o1, vs);
    __syncthreads();
    wmul<true>(Ta, X, W1, b10, b11, o0, o1, vs);
    amul(X, Tb, As, o0, o1, vs);
    __syncthreads();
    wmul<true>(Tb, X, W2, b20, b21, o0, o1, vs);
    amul(X, Ta, As, o0, o1, vs);
    __syncthreads();
    wmul<false>(Ta, Tb, W3, b30, b31, o0, o1, vs);
    __syncthreads();
}

// Final layer (W4, no tanh): k = W4 * Tb + b4, into named kernel-scope arrays.
// MACRO (not a function) so the destination arrays are never address-escaped.
#define WMUL_K(K0, K1) do {                                                            \
    _Pragma("unroll")                                                                  \
    for (int j = 0; j < 7; ++j) { K0[j] = b40; K1[j] = b41; }                          \
    _Pragma("unroll")                                                                  \
    for (int cb = 0; cb < 16; ++cb) {                                                  \
        float4 w0 = *(const float4*)(W4 + o0 * 64 + 4 * cb);                           \
        float4 w1 = *(const float4*)(W4 + o1 * 64 + 4 * cb);                           \
        _Pragma("unroll")                                                              \
        for (int j = 0; j < 7; ++j) {                                                  \
            float4 t = *(const float4*)(Tb + (vs + 4 * j) * CP + 4 * cb);              \
            K0[j] = fmaf(w0.x, t.x, fmaf(w0.y, t.y, fmaf(w0.z, t.z, fmaf(w0.w, t.w, K0[j])))); \
            K1[j] = fmaf(w1.x, t.x, fmaf(w1.y, t.y, fmaf(w1.z, t.z, fmaf(w1.w, t.w, K1[j])))); \
        }                                                                              \
    }                                                                                  \
} while (0)

// blocks 0..511: scan (b = blk, 32 sequential steps, y carried in registers)
// blocks 512..16895: z_hat (one step per (b,t))
__global__ void __launch_bounds__(NTH, 3)
rk4_both(const float* __restrict__ z, float* __restrict__ out,
         const float* __restrict__ Ag, const float* __restrict__ pe,
         const float* __restrict__ W1, const float* __restrict__ B1,
         const float* __restrict__ W2, const float* __restrict__ B2,
         const float* __restrict__ W3, const float* __restrict__ B3,
         const float* __restrict__ W4, const float* __restrict__ B4)
{
    __shared__ float X[64 * XW];
    __shared__ float Ta[NV * CP];
    __shared__ float Tb[NV * CP];
    __shared__ float As[NV * XW];

    int tid = threadIdx.x;
    int oq = tid >> 2, vs = tid & 3;
    int o0 = oq, o1 = oq + 32;

    int blk = blockIdx.x;
    bool scan = (blk < 512);
    int b, t_src, nsteps;
    if (scan) { b = blk; t_src = 31; nsteps = 32; }
    else      { int q = blk - 512; b = q >> 5; t_src = q & 31; nsteps = 1; }

    // stage A (zero pads, then fill)
    for (int i = tid; i < NV * XW; i += NTH) As[i] = 0.f;
    __syncthreads();
    for (int i = tid; i < 25 * 25; i += NTH) { int v = i / 25, u = i - v * 25; As[v * XW + u] = Ag[i]; }
    __syncthreads();

    float b10 = B1[o0], b11 = B1[o1], b20 = B2[o0], b21 = B2[o1];
    float b30 = B3[o0], b31 = B3[o1], b40 = B4[o0], b41 = B4[o1];

    // load y into registers (pad strips -> 0)
    const float* zb = z + (size_t)b * 64 * 64 * 25;
    float* outb = out + (size_t)b * 64 * 64 * 25;
    float y0[7], y1[7];
    #pragma unroll
    for (int j = 0; j < 7; ++j) {
        int v = vs + 4 * j;
        y0[j] = (v < 25) ? zb[((size_t)o0 * 64 + t_src) * 25 + v] : 0.f;
        y1[j] = (v < 25) ? zb[((size_t)o1 * 64 + t_src) * 25 + v] : 0.f;
    }

    for (int s = 0; s < nsteps; ++s) {
        int pr = scan ? s : 0;
        float pe00 = pe[pr * 64 + o0], pe01 = pe[pr * 64 + o1];
        float pe10 = pe[(pr + 1) * 64 + o0], pe11 = pe[(pr + 1) * 64 + o1];

        float kS0[7], kS1[7], kT0[7], kT1[7], kU0[7], kU1[7];

        // X1 = y + pe0   (f adds pe to its input; fold it into X directly)
        #pragma unroll
        for (int j = 0; j < 7; ++j) {
            int v = vs + 4 * j;
            X[o0 * XW + v] = y0[j] + pe00;
            X[o1 * XW + v] = y1[j] + pe01;
        }
        ode_head(X, Ta, Tb, As, W1, b10, b11, W2, b20, b21, W3, b30, b31, o0, o1, vs);
        WMUL_K(kS0, kS1);                       // kS = k1

        // X2 = y + k1/3 + pe0
        #pragma unroll
        for (int j = 0; j < 7; ++j) {
            int v = vs + 4 * j;
            X[o0 * XW + v] = y0[j] + kS0[j] * (1.f / 3.f) + pe00;
            X[o1 * XW + v] = y1[j] + kS1[j] * (1.f / 3.f) + pe01;
        }
        ode_head(X, Ta, Tb, As, W1, b10, b11, W2, b20, b21, W3, b30, b31, o0, o1, vs);
        WMUL_K(kT0, kT1);                       // kT = k2

        // X3 = y - k1/3 + k2 + pe0
        #pragma unroll
        for (int j = 0; j < 7; ++j) {
            int v = vs + 4 * j;
            X[o0 * XW + v] = y0[j] - kS0[j] * (1.f / 3.f) + kT0[j] + pe00;
            X[o1 * XW + v] = y1[j] - kS1[j] * (1.f / 3.f) + kT1[j] + pe01;
        }
        ode_head(X, Ta, Tb, As, W1, b10, b11, W2, b20, b21, W3, b30, b31, o0, o1, vs);
        WMUL_K(kU0, kU1);                       // kU = k3

        // X4 = y + k1 - k2 + k3 + pe1 ; S = k1 + 3(k2 + k3)
        #pragma unroll
        for (int j = 0; j < 7; ++j) {
            int v = vs + 4 * j;
            X[o0 * XW + v] = y0[j] + kS0[j] - kT0[j] + kU0[j] + pe10;
            X[o1 * XW + v] = y1[j] + kS1[j] - kT1[j] + kU1[j] + pe11;
            kS0[j] = kS0[j] + 3.f * (kT0[j] + kU0[j]);
            kS1[j] = kS1[j] + 3.f * (kT1[j] + kU1[j]);
        }
        ode_head(X, Ta, Tb, As, W1, b10, b11, W2, b20, b21, W3, b30, b31, o0, o1, vs);
        WMUL_K(kT0, kT1);                       // kT = k4

        // y' = y + (S + k4)/8 ; store
        int t_dst = scan ? (32 + s) : t_src;
        #pragma unroll
        for (int j = 0; j < 7; ++j) {
            int v = vs + 4 * j;
            float n0 = y0[j] + (kS0[j] + kT0[j]) * 0.125f;
            float n1 = y1[j] + (kS1[j] + kT1[j]) * 0.125f;
            y0[j] = n0; y1[j] = n1;
            if (v < 25) {
                outb[((size_t)o0 * 64 + t_dst) * 25 + v] = n0;
                outb[((size_t)o1 * 64 + t_dst) * 25 + v] = n1;
            }
        }
    }
}

__global__ void pe_kernel(float* __restrict__ pe) {
    int idx = blockIdx.x * blockDim.x + threadIdx.x;
    if (idx >= 64 * 64) return;
    int t = idx >> 6, c = idx & 63;
    int i2 = c & ~1;
    float div = expf((float)i2 * (-logf(10000.0f) / 64.0f));
    float arg = (float)t * div;
    pe[idx] = (c & 1) ? cosf(arg) : sinf(arg);
}

extern "C" void kernel_launch(void* const* d_in, const int* in_sizes, int n_in,
                              void* d_out, int out_size, void* d_ws, size_t ws_size,
                              hipStream_t stream) {
    const float* z  = (const float*)d_in[0];
    const float* A  = (const float*)d_in[1];
    const float* w1 = (const float*)d_in[2];
    const float* b1 = (const float*)d_in[3];
    const float* w2 = (const float*)d_in[4];
    const float* b2 = (const float*)d_in[5];
    const float* w3 = (const float*)d_in[6];
    const float* b3 = (const float*)d_in[7];
    const float* w4 = (const float*)d_in[8];
    const float* b4 = (const float*)d_in[9];
    float* out = (float*)d_out;
    float* pe  = (float*)d_ws;   // 64*64 floats

    pe_kernel<<<16, 256, 0, stream>>>(pe);

    // one fused dispatch: blocks 0..511 = autoregressive scan (long critical
    // path, dispatched first); blocks 512..16895 = z_hat throughput work
    rk4_both<<<512 + 512 * 32, NTH, 0, stream>>>(
        z, out, A, pe, w1, b1, w2, b2, w3, b3, w4, b4);
}

// Round 8
// 15593.480 us; speedup vs baseline: 1.4765x; 1.4765x over previous
//
#include <hip/hip_runtime.h>
#include <math.h>

#define NTH 256
#define XW 28      // X row width ([c][v] layout, cols 25..27 pad)
#define CP 68      // T row width ([v][c] layout, cols 64..67 pad)
#define NV 28

__device__ __forceinline__ float tanh_fast(float x) {
    float t = fminf(fmaxf(2.0f * x, -30.0f), 30.0f);
    float e = __expf(t);
    return (e - 1.0f) / (e + 1.0f);
}

// T[v][o] = sum_u X[o][u] * As[v][u]  for v in this thread's strip (one row o)
__device__ __forceinline__ void amul(const float* __restrict__ X, float* __restrict__ T,
                                     const float* __restrict__ As, int o, int vs)
{
    float a[7];
    #pragma unroll
    for (int j = 0; j < 7; ++j) a[j] = 0.f;
    const float* xp = X + o * XW;
    #pragma unroll
    for (int ub = 0; ub < 7; ++ub) {
        float4 x = *(const float4*)(xp + 4 * ub);
        #pragma unroll
        for (int j = 0; j < 7; ++j) {
            float4 aa = *(const float4*)(As + (vs + 4 * j) * XW + 4 * ub);
            a[j] = fmaf(x.x, aa.x, fmaf(x.y, aa.y, fmaf(x.z, aa.z, fmaf(x.w, aa.w, a[j]))));
        }
    }
    #pragma unroll
    for (int j = 0; j < 7; ++j) T[(vs + 4 * j) * CP + o] = a[j];
}

// acc = W[o][:] . T[v][:] + b ; TOX=true -> X[o][v]=tanh ; TOX=false -> Tout[v][o]=tanh
template<bool TOX>
__device__ __forceinline__ void wmul(const float* __restrict__ T, float* __restrict__ outp,
                                     const float* __restrict__ Wg, float b, int o, int vs)
{
    float a[7];
    #pragma unroll
    for (int j = 0; j < 7; ++j) a[j] = b;
    const float* wp = Wg + o * 64;
    #pragma unroll
    for (int cb = 0; cb < 16; ++cb) {
        float4 w = *(const float4*)(wp + 4 * cb);
        #pragma unroll
        for (int j = 0; j < 7; ++j) {
            float4 t = *(const float4*)(T + (vs + 4 * j) * CP + 4 * cb);
            a[j] = fmaf(w.x, t.x, fmaf(w.y, t.y, fmaf(w.z, t.z, fmaf(w.w, t.w, a[j]))));
        }
    }
    #pragma unroll
    for (int j = 0; j < 7; ++j) {
        int v = vs + 4 * j;
        if (TOX) outp[o * XW + v] = tanh_fast(a[j]);
        else     outp[v * CP + o] = tanh_fast(a[j]);
    }
}

// First 3 layers of f: X -> (A,W1,tanh) -> (A,W2,tanh) -> (A,W3,tanh) -> Tb[v][c].
__device__ __forceinline__ void ode_head(float* X, float* Ta, float* Tb, const float* As,
    const float* W1, float b1r, const float* W2, float b2r, const float* W3, float b3r,
    int o, int vs)
{
    amul(X, Ta, As, o, vs);
    __syncthreads();
    wmul<true>(Ta, X, W1, b1r, o, vs);
    amul(X, Tb, As, o, vs);
    __syncthreads();
    wmul<true>(Tb, X, W2, b2r, o, vs);
    amul(X, Ta, As, o, vs);
    __syncthreads();
    wmul<false>(Ta, Tb, W3, b3r, o, vs);
    __syncthreads();
}

// Final layer (W4, no tanh): K[j] = W4[o][:] . Tb[v][:] + b4. Macro in kernel scope.
#define WMUL_K(K) do {                                                                 \
    _Pragma("unroll")                                                                  \
    for (int j = 0; j < 7; ++j) K[j] = b4r;                                            \
    _Pragma("unroll")                                                                  \
    for (int cb = 0; cb < 16; ++cb) {                                                  \
        float4 w = *(const float4*)(W4 + o * 64 + 4 * cb);                             \
        _Pragma("unroll")                                                              \
        for (int j = 0; j < 7; ++j) {                                                  \
            float4 t = *(const float4*)(Tb + (vs + 4 * j) * CP + 4 * cb);              \
            K[j] = fmaf(w.x, t.x, fmaf(w.y, t.y, fmaf(w.z, t.z, fmaf(w.w, t.w, K[j]))));\
        }                                                                              \
    }                                                                                  \
} while (0)

// blocks 0..511: scan (b = blk, 32 sequential steps, y carried in registers)
// blocks 512..16895: z_hat (one step per (b,t))
__global__ void __launch_bounds__(NTH, 4)
rk4_both(const float* __restrict__ z, float* __restrict__ out,
         const float* __restrict__ Ag, const float* __restrict__ pe,
         const float* __restrict__ W1, const float* __restrict__ B1,
         const float* __restrict__ W2, const float* __restrict__ B2,
         const float* __restrict__ W3, const float* __restrict__ B3,
         const float* __restrict__ W4, const float* __restrict__ B4)
{
    __shared__ float X[64 * XW];
    __shared__ float Ta[NV * CP];
    __shared__ float Tb[NV * CP];
    __shared__ float As[NV * XW];

    int tid = threadIdx.x;
    int o = tid >> 2, vs = tid & 3;   // one channel row per thread

    int blk = blockIdx.x;
    bool scan = (blk < 512);
    int b, t_src, nsteps;
    if (scan) { b = blk; t_src = 31; nsteps = 32; }
    else      { int q = blk - 512; b = q >> 5; t_src = q & 31; nsteps = 1; }

    // stage A (zero pads, then fill)
    for (int i = tid; i < NV * XW; i += NTH) As[i] = 0.f;
    __syncthreads();
    for (int i = tid; i < 25 * 25; i += NTH) { int v = i / 25, u = i - v * 25; As[v * XW + u] = Ag[i]; }
    __syncthreads();

    float b1r = B1[o], b2r = B2[o], b3r = B3[o], b4r = B4[o];

    // load y into registers (pad strips -> 0)
    const float* zb = z + (size_t)b * 64 * 64 * 25;
    float* outb = out + (size_t)b * 64 * 64 * 25;
    float y[7];
    #pragma unroll
    for (int j = 0; j < 7; ++j) {
        int v = vs + 4 * j;
        y[j] = (v < 25) ? zb[((size_t)o * 64 + t_src) * 25 + v] : 0.f;
    }

    for (int s = 0; s < nsteps; ++s) {
        int pr = scan ? s : 0;
        float pe0 = pe[pr * 64 + o];
        float pe1 = pe[(pr + 1) * 64 + o];

        float kS[7], kT[7], kU[7];

        // X1 = y + pe0
        #pragma unroll
        for (int j = 0; j < 7; ++j) X[o * XW + vs + 4 * j] = y[j] + pe0;
        ode_head(X, Ta, Tb, As, W1, b1r, W2, b2r, W3, b3r, o, vs);
        WMUL_K(kS);                         // kS = k1

        // X2 = y + k1/3 + pe0
        #pragma unroll
        for (int j = 0; j < 7; ++j) X[o * XW + vs + 4 * j] = y[j] + kS[j] * (1.f / 3.f) + pe0;
        ode_head(X, Ta, Tb, As, W1, b1r, W2, b2r, W3, b3r, o, vs);
        WMUL_K(kT);                         // kT = k2

        // X3 = y - k1/3 + k2 + pe0
        #pragma unroll
        for (int j = 0; j < 7; ++j) X[o * XW + vs + 4 * j] = y[j] - kS[j] * (1.f / 3.f) + kT[j] + pe0;
        ode_head(X, Ta, Tb, As, W1, b1r, W2, b2r, W3, b3r, o, vs);
        WMUL_K(kU);                         // kU = k3

        // X4 = y + k1 - k2 + k3 + pe1 ; fold S = k1 + 3(k2+k3) into kS
        #pragma unroll
        for (int j = 0; j < 7; ++j) {
            X[o * XW + vs + 4 * j] = y[j] + kS[j] - kT[j] + kU[j] + pe1;
            kS[j] = kS[j] + 3.f * (kT[j] + kU[j]);
        }
        ode_head(X, Ta, Tb, As, W1, b1r, W2, b2r, W3, b3r, o, vs);
        WMUL_K(kT);                         // kT = k4

        // y' = y + (S + k4)/8 ; store
        int t_dst = scan ? (32 + s) : t_src;
        #pragma unroll
        for (int j = 0; j < 7; ++j) {
            int v = vs + 4 * j;
            float n = y[j] + (kS[j] + kT[j]) * 0.125f;
            y[j] = n;
            if (v < 25) outb[((size_t)o * 64 + t_dst) * 25 + v] = n;
        }
    }
}

__global__ void pe_kernel(float* __restrict__ pe) {
    int idx = blockIdx.x * blockDim.x + threadIdx.x;
    if (idx >= 64 * 64) return;
    int t = idx >> 6, c = idx & 63;
    int i2 = c & ~1;
    float div = expf((float)i2 * (-logf(10000.0f) / 64.0f));
    float arg = (float)t * div;
    pe[idx] = (c & 1) ? cosf(arg) : sinf(arg);
}

extern "C" void kernel_launch(void* const* d_in, const int* in_sizes, int n_in,
                              void* d_out, int out_size, void* d_ws, size_t ws_size,
                              hipStream_t stream) {
    const float* z  = (const float*)d_in[0];
    const float* A  = (const float*)d_in[1];
    const float* w1 = (const float*)d_in[2];
    const float* b1 = (const float*)d_in[3];
    const float* w2 = (const float*)d_in[4];
    const float* b2 = (const float*)d_in[5];
    const float* w3 = (const float*)d_in[6];
    const float* b3 = (const float*)d_in[7];
    const float* w4 = (const float*)d_in[8];
    const float* b4 = (const float*)d_in[9];
    float* out = (float*)d_out;
    float* pe  = (float*)d_ws;   // 64*64 floats

    pe_kernel<<<16, 256, 0, stream>>>(pe);

    // one fused dispatch: blocks 0..511 = autoregressive scan (long critical
    // path, dispatched first); blocks 512..16895 = z_hat throughput work
    rk4_both<<<512 + 512 * 32, NTH, 0, stream>>>(
        z, out, A, pe, w1, b1, w2, b2, w3, b3, w4, b4);
}